// Round 1
// baseline (1229.378 us; speedup 1.0000x reference)
//
#include <hip/hip_runtime.h>
#include <hip/hip_bf16.h>
#include <math.h>

#define SCAN_CHUNK 2048
#define DEG_BINS 256

typedef _Float16 half2v __attribute__((ext_vector_type(2)));
typedef _Float16 half8 __attribute__((ext_vector_type(8)));
typedef _Float16 half16v __attribute__((ext_vector_type(16)));
typedef float floatx4 __attribute__((ext_vector_type(4)));

#if defined(__has_builtin)
#if __has_builtin(__builtin_amdgcn_fdot2)
#define USE_FDOT2 1
#endif
#endif

// ---------------- CSR build ----------------

__global__ void hist_kernel(const int* __restrict__ dst, int* __restrict__ counts, int e) {
    int i = blockIdx.x * blockDim.x + threadIdx.x;
    if (i < e) atomicAdd(&counts[dst[i]], 1);
}

__global__ __launch_bounds__(256) void scan_block_sums(const int* __restrict__ counts,
                                                       int* __restrict__ bsum, int n) {
    __shared__ int sd[256];
    int t = threadIdx.x;
    int base = blockIdx.x * SCAN_CHUNK + t * 8;
    int s = 0;
#pragma unroll
    for (int j = 0; j < 8; ++j) {
        int idx = base + j;
        if (idx < n) s += counts[idx];
    }
    sd[t] = s;
    __syncthreads();
    for (int off = 128; off > 0; off >>= 1) {
        if (t < off) sd[t] += sd[t + off];
        __syncthreads();
    }
    if (t == 0) bsum[blockIdx.x] = sd[0];
}

// single-wave exclusive scan over nb <= 64 block sums
__global__ void scan_wave(int* bsum, int nb) {
    int lane = threadIdx.x;
    int orig = (lane < nb) ? bsum[lane] : 0;
    int v = orig;
    for (int off = 1; off < 64; off <<= 1) {
        int t = __shfl_up(v, off, 64);
        if (lane >= off) v += t;
    }
    if (lane < nb) bsum[lane] = v - orig;  // exclusive
}

__global__ __launch_bounds__(256) void scan_write(const int* __restrict__ counts,
                                                  const int* __restrict__ bsum,
                                                  int* __restrict__ row_ptr,
                                                  int* __restrict__ cursor,
                                                  int n, int total) {
    __shared__ int sd[256];
    int t = threadIdx.x;
    int base = blockIdx.x * SCAN_CHUNK + t * 8;
    int v[8];
    int s = 0;
#pragma unroll
    for (int j = 0; j < 8; ++j) {
        int idx = base + j;
        v[j] = (idx < n) ? counts[idx] : 0;
        s += v[j];
    }
    sd[t] = s;
    __syncthreads();
    for (int off = 1; off < 256; off <<= 1) {
        int tmp = 0;
        if (t >= off) tmp = sd[t - off];
        __syncthreads();
        if (t >= off) sd[t] += tmp;
        __syncthreads();
    }
    int run = bsum[blockIdx.x] + sd[t] - s;
#pragma unroll
    for (int j = 0; j < 8; ++j) {
        int idx = base + j;
        if (idx < n) {
            row_ptr[idx] = run;
            cursor[idx] = run;
            run += v[j];
        }
    }
    if (blockIdx.x == 0 && t == 0) row_ptr[n] = total;
}

__global__ void fill_csr(const int* __restrict__ dst, int* cursor,
                         int* __restrict__ csr, int e) {
    int i = blockIdx.x * blockDim.x + threadIdx.x;
    if (i < e) {
        int p = atomicAdd(&cursor[dst[i]], 1);
        csr[p] = i;
    }
}

// ---------------- degree counting-sort of nodes ----------------
// counts[] (from hist_kernel) IS the per-node degree. Bin nodes by degree so
// every edge_attn wave serves 8 equal-degree nodes (kills max-of-8 imbalance).

__global__ __launch_bounds__(256) void deg_hist(const int* __restrict__ counts,
                                                int* __restrict__ bins, int n) {
    int i = blockIdx.x * blockDim.x + threadIdx.x;
    if (i < n) {
        int d = counts[i];
        if (d > DEG_BINS - 1) d = DEG_BINS - 1;
        atomicAdd(&bins[d], 1);
    }
}

__global__ __launch_bounds__(256) void deg_scan(const int* __restrict__ bins,
                                                int* __restrict__ bcur) {
    __shared__ int sd[256];
    int t = threadIdx.x;
    int v = bins[t];
    sd[t] = v;
    __syncthreads();
    for (int off = 1; off < 256; off <<= 1) {
        int tmp = 0;
        if (t >= off) tmp = sd[t - off];
        __syncthreads();
        if (t >= off) sd[t] += tmp;
        __syncthreads();
    }
    bcur[t] = sd[t] - v;  // exclusive
}

__global__ __launch_bounds__(256) void deg_scatter(const int* __restrict__ counts,
                                                   int* __restrict__ bcur,
                                                   int* __restrict__ perm, int n) {
    int i = blockIdx.x * blockDim.x + threadIdx.x;
    if (i < n) {
        int d = counts[i];
        if (d > DEG_BINS - 1) d = DEG_BINS - 1;
        int p = atomicAdd(&bcur[d], 1);
        perm[p] = i;
    }
}

// ---------------- fp16 prep ----------------

__global__ __launch_bounds__(256) void convert_x(const float* __restrict__ x,
                                                 _Float16* __restrict__ xh, int total8) {
    int i = blockIdx.x * blockDim.x + threadIdx.x;
    if (i < total8) {
        const float4* s = (const float4*)x + i * 2;
        float4 a = s[0], b = s[1];
        half8 h;
        h[0] = (_Float16)a.x; h[1] = (_Float16)a.y; h[2] = (_Float16)a.z; h[3] = (_Float16)a.w;
        h[4] = (_Float16)b.x; h[5] = (_Float16)b.y; h[6] = (_Float16)b.z; h[7] = (_Float16)b.w;
        *((half8*)xh + i) = h;
    }
}

// transpose+convert W [k][n] fp32 -> wt [n][k] fp16; blockIdx.x selects matrix
__global__ __launch_bounds__(256) void prep_w(const float* __restrict__ Wq,
                                              const float* __restrict__ Wk,
                                              const float* __restrict__ Wv,
                                              _Float16* __restrict__ wt) {
    const float* W = (blockIdx.x == 0) ? Wq : (blockIdx.x == 1) ? Wk : Wv;
    _Float16* out = wt + (size_t)blockIdx.x * 16384;
    int t = threadIdx.x;
    for (int r = 0; r < 64; ++r) {
        int idx = r * 256 + t;          // idx = k*128 + n
        int k = idx >> 7, nn = idx & 127;
        out[nn * 128 + k] = (_Float16)W[idx];
    }
}

// ---------------- QKV projection: fp16 MFMA ----------------

#define LDP 136  // 128 + 8 halfs pad

__global__ __launch_bounds__(256) void qkv_mfma(
    const _Float16* __restrict__ xh, const _Float16* __restrict__ wt,
    const float* __restrict__ bq, const float* __restrict__ bk,
    const float* __restrict__ bv,
    _Float16* __restrict__ qh, _Float16* __restrict__ kh, _Float16* __restrict__ vh,
    int n) {
    __shared__ __align__(16) _Float16 xs[128 * LDP];
    __shared__ __align__(16) _Float16 ws[128 * LDP];

    int t = threadIdx.x;
    int tile0 = blockIdx.x * 128;
    int sel = blockIdx.y;
    const _Float16* wsel = wt + (size_t)sel * 16384;
    const float* bias = (sel == 0) ? bq : (sel == 1) ? bk : bv;
    _Float16* out = (sel == 0) ? qh : (sel == 1) ? kh : vh;

#pragma unroll
    for (int r = 0; r < 8; ++r) {
        int id = r * 256 + t;
        int row = id >> 4, c8 = id & 15;
        int grow = tile0 + row;
        half8 val = (half8)(_Float16)0;
        if (grow < n) val = *((const half8*)(xh + (size_t)grow * 128) + c8);
        *((half8*)(xs + row * LDP) + c8) = val;
        half8 wv = *((const half8*)(wsel + row * 128) + c8);
        *((half8*)(ws + row * LDP) + c8) = wv;
    }
    __syncthreads();

    int wave = t >> 6, lane = t & 63;
    int wm = (wave & 1) * 64, wn = (wave >> 1) * 64;
    int lrow = lane & 15, quad = lane >> 4;

    floatx4 acc[4][4];
#pragma unroll
    for (int i = 0; i < 4; ++i)
#pragma unroll
        for (int j = 0; j < 4; ++j) acc[i][j] = (floatx4)0.f;

#pragma unroll
    for (int kk = 0; kk < 4; ++kk) {
        int kbase = kk * 32 + quad * 8;
        half8 a[4], b[4];
#pragma unroll
        for (int i = 0; i < 4; ++i)
            a[i] = *(const half8*)(xs + (wm + i * 16 + lrow) * LDP + kbase);
#pragma unroll
        for (int j = 0; j < 4; ++j)
            b[j] = *(const half8*)(ws + (wn + j * 16 + lrow) * LDP + kbase);
#pragma unroll
        for (int i = 0; i < 4; ++i)
#pragma unroll
            for (int j = 0; j < 4; ++j)
                acc[i][j] = __builtin_amdgcn_mfma_f32_16x16x32_f16(a[i], b[j], acc[i][j], 0, 0, 0);
    }

#pragma unroll
    for (int i = 0; i < 4; ++i) {
#pragma unroll
        for (int j = 0; j < 4; ++j) {
            int col = wn + j * 16 + lrow;
            float bv_ = bias[col];
#pragma unroll
            for (int r = 0; r < 4; ++r) {
                int row = wm + i * 16 + quad * 4 + r;
                int grow = tile0 + row;
                if (grow < n) out[(size_t)grow * 128 + col] = (_Float16)(acc[i][j][r] + bv_);
            }
        }
    }
}

// ---------------- Node-centric attention: pipelined gathers ----------------
// p_eh = mix_eh * exp(dot/4); attn = p / sum(p). Scores bounded so no max needed.
// 8 threads/node (1 head each), 32 nodes/block. Nodes are served in degree-sorted
// order (heaviest first) via perm[] so each wave's 8 nodes have equal degree.
// Software pipeline: metadata 2 edges ahead, K/V rows 1 edge ahead.

__global__ __launch_bounds__(256) void edge_attn(
    const _Float16* __restrict__ qh, const _Float16* __restrict__ kh,
    const _Float16* __restrict__ vh, const float* __restrict__ pi,
    const float* __restrict__ view_w, const int* __restrict__ src,
    const int* __restrict__ row_ptr, const int* __restrict__ csr,
    const int* __restrict__ perm,
    float* __restrict__ node_out, float* __restrict__ invb,
    _Float16* __restrict__ pbuf, int n) {
    int t = threadIdx.x;
    int gid = blockIdx.x * 32 + (t >> 3);
    if (gid >= n) return;
    int node = perm[n - 1 - gid];   // heaviest-degree nodes first (LPT)
    int h = t & 7;

    const half16v qv = *(const half16v*)(qh + (size_t)node * 128 + h * 16);
    const _Float16* kbase = kh + h * 16;
    const _Float16* vbase = vh + h * 16;

    float p0 = pi[node * 24 + h * 3 + 0];
    float p1 = pi[node * 24 + h * 3 + 1];
    float p2 = pi[node * 24 + h * 3 + 2];
    int beg = row_ptr[node], end = row_ptr[node + 1];

    float l = 0.f;
    float acc[16];
#pragma unroll
    for (int j = 0; j < 16; ++j) acc[j] = 0.f;

    // pipeline state: meta for current (0) and next (1); K/V for current loaded
    int e0 = 0, s0 = 0, e1 = 0, s1 = 0;
    float w0a = 0.f, w0b = 0.f, w0c = 0.f;
    float w1a = 0.f, w1b = 0.f, w1c = 0.f;
    half16v kc = (half16v)(_Float16)0, vc = (half16v)(_Float16)0;

    if (beg < end) {
        e0 = csr[beg]; s0 = src[e0];
        const float* vp = view_w + (size_t)e0 * 3;
        w0a = vp[0]; w0b = vp[1]; w0c = vp[2];
        kc = *(const half16v*)(kbase + (size_t)s0 * 128);
        vc = *(const half16v*)(vbase + (size_t)s0 * 128);
    }
    if (beg + 1 < end) {
        e1 = csr[beg + 1]; s1 = src[e1];
        const float* vp = view_w + (size_t)e1 * 3;
        w1a = vp[0]; w1b = vp[1]; w1c = vp[2];
    }

    for (int i = beg; i < end; ++i) {
        // issue K/V gather for edge i+1 (address known from meta prefetch)
        half16v kn = kc, vn = vc;
        if (i + 1 < end) {
            kn = *(const half16v*)(kbase + (size_t)s1 * 128);
            vn = *(const half16v*)(vbase + (size_t)s1 * 128);
        }
        // prefetch metadata for edge i+2
        int e2 = 0, s2 = 0;
        float w2a = 0.f, w2b = 0.f, w2c = 0.f;
        if (i + 2 < end) {
            e2 = csr[i + 2]; s2 = src[e2];
            const float* vp = view_w + (size_t)e2 * 3;
            w2a = vp[0]; w2b = vp[1]; w2c = vp[2];
        }

        float mix = fmaf(p0, w0a, fmaf(p1, w0b, p2 * w0c));
        float d = 0.f;
#ifdef USE_FDOT2
#pragma unroll
        for (int j = 0; j < 8; ++j) {
            half2v a, b;
            a[0] = qv[2 * j]; a[1] = qv[2 * j + 1];
            b[0] = kc[2 * j]; b[1] = kc[2 * j + 1];
            d = __builtin_amdgcn_fdot2(a, b, d, false);
        }
#else
#pragma unroll
        for (int j = 0; j < 16; ++j) d = fmaf((float)qv[j], (float)kc[j], d);
#endif

        float p = (mix > 0.f) ? mix * __expf(d * 0.25f) : 0.f;
        pbuf[(size_t)e0 * 8 + h] = (_Float16)p;
        l += p;
#pragma unroll
        for (int j = 0; j < 16; ++j) acc[j] = fmaf(p, (float)vc[j], acc[j]);

        // rotate pipeline
        e0 = e1; s0 = s1; w0a = w1a; w0b = w1b; w0c = w1c;
        e1 = e2; s1 = s2; w1a = w2a; w1b = w2b; w1c = w2c;
        kc = kn; vc = vn;
    }

    float inv = 1.f / fmaxf(l, 1e-8f);
    invb[(size_t)node * 8 + h] = inv;

    float4* op = (float4*)(node_out + (size_t)node * 128 + h * 16);
#pragma unroll
    for (int j = 0; j < 4; ++j)
        op[j] = make_float4(acc[4 * j] * inv, acc[4 * j + 1] * inv,
                            acc[4 * j + 2] * inv, acc[4 * j + 3] * inv);
}

// ---------------- edge-parallel attention normalize (coalesced) ----------------

__global__ __launch_bounds__(256) void attn_norm(
    const _Float16* __restrict__ pbuf, const int* __restrict__ dst,
    const float* __restrict__ invb, float* __restrict__ attn_out, int e) {
    int i = blockIdx.x * blockDim.x + threadIdx.x;
    if (i < e) {
        int d = dst[i];
        half8 p = *((const half8*)pbuf + i);
        const float4* iv = (const float4*)(invb + (size_t)d * 8);
        float4 i0 = iv[0], i1 = iv[1];
        float4* op = (float4*)(attn_out + (size_t)i * 8);
        op[0] = make_float4((float)p[0] * i0.x, (float)p[1] * i0.y,
                            (float)p[2] * i0.z, (float)p[3] * i0.w);
        op[1] = make_float4((float)p[4] * i1.x, (float)p[5] * i1.y,
                            (float)p[6] * i1.z, (float)p[7] * i1.w);
    }
}

// ---------------- launch ----------------

extern "C" void kernel_launch(void* const* d_in, const int* in_sizes, int n_in,
                              void* d_out, int out_size, void* d_ws, size_t ws_size,
                              hipStream_t stream) {
    const float* x  = (const float*)d_in[0];
    const float* pi = (const float*)d_in[1];
    const float* vw = (const float*)d_in[2];
    const float* Wq = (const float*)d_in[3];
    const float* bq = (const float*)d_in[4];
    const float* Wk = (const float*)d_in[5];
    const float* bk = (const float*)d_in[6];
    const float* Wv = (const float*)d_in[7];
    const float* bv = (const float*)d_in[8];
    const int* src  = (const int*)d_in[9];
    const int* dst  = (const int*)d_in[10];

    int n = in_sizes[0] / 128;  // 100000
    int e = in_sizes[9];        // 1600000

    _Float16* xh = (_Float16*)d_ws;
    _Float16* qh = xh + (size_t)n * 128;
    _Float16* kh = qh + (size_t)n * 128;
    _Float16* vh = kh + (size_t)n * 128;
    _Float16* wt = vh + (size_t)n * 128;
    _Float16* pbuf = wt + 3 * 16384;
    float* invb  = (float*)(pbuf + (size_t)e * 8);
    int* counts  = (int*)(invb + (size_t)n * 8);
    int* cursor  = counts + n;
    int* row_ptr = cursor + n;
    int* csr     = row_ptr + n + 1;
    int* bsum    = csr + e;
    int* perm    = bsum + 64;
    int* bins    = perm + n;
    int* bcur    = bins + DEG_BINS;

    float* node_out = (float*)d_out;
    float* attn_out = node_out + (size_t)n * 128;

    hipMemsetAsync(counts, 0, (size_t)n * sizeof(int), stream);
    hipMemsetAsync(bins, 0, DEG_BINS * sizeof(int), stream);

    int eb = (e + 255) / 256;
    hist_kernel<<<eb, 256, 0, stream>>>(dst, counts, e);

    // degree counting-sort (counts[] holds per-node degree after hist)
    int nblk = (n + 255) / 256;
    deg_hist<<<nblk, 256, 0, stream>>>(counts, bins, n);
    deg_scan<<<1, 256, 0, stream>>>(bins, bcur);
    deg_scatter<<<nblk, 256, 0, stream>>>(counts, bcur, perm, n);

    int nb = (n + SCAN_CHUNK - 1) / SCAN_CHUNK;  // 49
    scan_block_sums<<<nb, 256, 0, stream>>>(counts, bsum, n);
    scan_wave<<<1, 64, 0, stream>>>(bsum, nb);
    scan_write<<<nb, 256, 0, stream>>>(counts, bsum, row_ptr, cursor, n, e);
    fill_csr<<<eb, 256, 0, stream>>>(dst, cursor, csr, e);

    int tot8 = (n * 128) / 8;
    convert_x<<<(tot8 + 255) / 256, 256, 0, stream>>>(x, xh, tot8);
    prep_w<<<3, 256, 0, stream>>>(Wq, Wk, Wv, wt);

    int gtiles = (n + 127) / 128;
    qkv_mfma<<<dim3(gtiles, 3), 256, 0, stream>>>(xh, wt, bq, bk, bv, qh, kh, vh, n);

    int gb = (n + 31) / 32;
    edge_attn<<<gb, 256, 0, stream>>>(qh, kh, vh, pi, vw, src, row_ptr, csr, perm,
                                      node_out, invb, pbuf, n);
    attn_norm<<<eb, 256, 0, stream>>>(pbuf, dst, invb, attn_out, e);
}

// Round 2
// 646.263 us; speedup vs baseline: 1.9023x; 1.9023x over previous
//
#include <hip/hip_runtime.h>
#include <hip/hip_bf16.h>
#include <math.h>

#define SCAN_CHUNK 2048

typedef _Float16 half2v __attribute__((ext_vector_type(2)));
typedef _Float16 half8 __attribute__((ext_vector_type(8)));
typedef _Float16 half16v __attribute__((ext_vector_type(16)));
typedef float floatx4 __attribute__((ext_vector_type(4)));

#if defined(__has_builtin)
#if __has_builtin(__builtin_amdgcn_fdot2)
#define USE_FDOT2 1
#endif
#endif

// ---------------- CSR build ----------------

__global__ void hist_kernel(const int* __restrict__ dst, int* __restrict__ counts, int e) {
    int i = blockIdx.x * blockDim.x + threadIdx.x;
    if (i < e) atomicAdd(&counts[dst[i]], 1);
}

__global__ __launch_bounds__(256) void scan_block_sums(const int* __restrict__ counts,
                                                       int* __restrict__ bsum, int n) {
    __shared__ int sd[256];
    int t = threadIdx.x;
    int base = blockIdx.x * SCAN_CHUNK + t * 8;
    int s = 0;
#pragma unroll
    for (int j = 0; j < 8; ++j) {
        int idx = base + j;
        if (idx < n) s += counts[idx];
    }
    sd[t] = s;
    __syncthreads();
    for (int off = 128; off > 0; off >>= 1) {
        if (t < off) sd[t] += sd[t + off];
        __syncthreads();
    }
    if (t == 0) bsum[blockIdx.x] = sd[0];
}

// single-wave exclusive scan over nb <= 64 block sums
__global__ void scan_wave(int* bsum, int nb) {
    int lane = threadIdx.x;
    int orig = (lane < nb) ? bsum[lane] : 0;
    int v = orig;
    for (int off = 1; off < 64; off <<= 1) {
        int t = __shfl_up(v, off, 64);
        if (lane >= off) v += t;
    }
    if (lane < nb) bsum[lane] = v - orig;  // exclusive
}

__global__ __launch_bounds__(256) void scan_write(const int* __restrict__ counts,
                                                  const int* __restrict__ bsum,
                                                  int* __restrict__ row_ptr,
                                                  int* __restrict__ cursor,
                                                  int n, int total) {
    __shared__ int sd[256];
    int t = threadIdx.x;
    int base = blockIdx.x * SCAN_CHUNK + t * 8;
    int v[8];
    int s = 0;
#pragma unroll
    for (int j = 0; j < 8; ++j) {
        int idx = base + j;
        v[j] = (idx < n) ? counts[idx] : 0;
        s += v[j];
    }
    sd[t] = s;
    __syncthreads();
    for (int off = 1; off < 256; off <<= 1) {
        int tmp = 0;
        if (t >= off) tmp = sd[t - off];
        __syncthreads();
        if (t >= off) sd[t] += tmp;
        __syncthreads();
    }
    int run = bsum[blockIdx.x] + sd[t] - s;
#pragma unroll
    for (int j = 0; j < 8; ++j) {
        int idx = base + j;
        if (idx < n) {
            row_ptr[idx] = run;
            cursor[idx] = run;
            run += v[j];
        }
    }
    if (blockIdx.x == 0 && t == 0) row_ptr[n] = total;
}

// fused edge record: (edge_id, src_node) -> one dwordx2 load in edge_attn
__global__ void fill_csr(const int* __restrict__ dst, const int* __restrict__ src,
                         int* cursor, int2* __restrict__ csr2, int e) {
    int i = blockIdx.x * blockDim.x + threadIdx.x;
    if (i < e) {
        int p = atomicAdd(&cursor[dst[i]], 1);
        csr2[p] = make_int2(i, src[i]);
    }
}

// ---------------- fp16 prep ----------------

__global__ __launch_bounds__(256) void convert_x(const float* __restrict__ x,
                                                 _Float16* __restrict__ xh, int total8) {
    int i = blockIdx.x * blockDim.x + threadIdx.x;
    if (i < total8) {
        const float4* s = (const float4*)x + i * 2;
        float4 a = s[0], b = s[1];
        half8 h;
        h[0] = (_Float16)a.x; h[1] = (_Float16)a.y; h[2] = (_Float16)a.z; h[3] = (_Float16)a.w;
        h[4] = (_Float16)b.x; h[5] = (_Float16)b.y; h[6] = (_Float16)b.z; h[7] = (_Float16)b.w;
        *((half8*)xh + i) = h;
    }
}

// transpose+convert W [k][n] fp32 -> wt [n][k] fp16; blockIdx.x selects matrix
__global__ __launch_bounds__(256) void prep_w(const float* __restrict__ Wq,
                                              const float* __restrict__ Wk,
                                              const float* __restrict__ Wv,
                                              _Float16* __restrict__ wt) {
    const float* W = (blockIdx.x == 0) ? Wq : (blockIdx.x == 1) ? Wk : Wv;
    _Float16* out = wt + (size_t)blockIdx.x * 16384;
    int t = threadIdx.x;
    for (int r = 0; r < 64; ++r) {
        int idx = r * 256 + t;          // idx = k*128 + n
        int k = idx >> 7, nn = idx & 127;
        out[nn * 128 + k] = (_Float16)W[idx];
    }
}

// ---------------- QKV projection: fp16 MFMA ----------------

#define LDP 136  // 128 + 8 halfs pad

__global__ __launch_bounds__(256) void qkv_mfma(
    const _Float16* __restrict__ xh, const _Float16* __restrict__ wt,
    const float* __restrict__ bq, const float* __restrict__ bk,
    const float* __restrict__ bv,
    _Float16* __restrict__ qh, _Float16* __restrict__ kh, _Float16* __restrict__ vh,
    int n) {
    __shared__ __align__(16) _Float16 xs[128 * LDP];
    __shared__ __align__(16) _Float16 ws[128 * LDP];

    int t = threadIdx.x;
    int tile0 = blockIdx.x * 128;
    int sel = blockIdx.y;
    const _Float16* wsel = wt + (size_t)sel * 16384;
    const float* bias = (sel == 0) ? bq : (sel == 1) ? bk : bv;
    _Float16* out = (sel == 0) ? qh : (sel == 1) ? kh : vh;

#pragma unroll
    for (int r = 0; r < 8; ++r) {
        int id = r * 256 + t;
        int row = id >> 4, c8 = id & 15;
        int grow = tile0 + row;
        half8 val = (half8)(_Float16)0;
        if (grow < n) val = *((const half8*)(xh + (size_t)grow * 128) + c8);
        *((half8*)(xs + row * LDP) + c8) = val;
        half8 wv = *((const half8*)(wsel + row * 128) + c8);
        *((half8*)(ws + row * LDP) + c8) = wv;
    }
    __syncthreads();

    int wave = t >> 6, lane = t & 63;
    int wm = (wave & 1) * 64, wn = (wave >> 1) * 64;
    int lrow = lane & 15, quad = lane >> 4;

    floatx4 acc[4][4];
#pragma unroll
    for (int i = 0; i < 4; ++i)
#pragma unroll
        for (int j = 0; j < 4; ++j) acc[i][j] = (floatx4)0.f;

#pragma unroll
    for (int kk = 0; kk < 4; ++kk) {
        int kbase = kk * 32 + quad * 8;
        half8 a[4], b[4];
#pragma unroll
        for (int i = 0; i < 4; ++i)
            a[i] = *(const half8*)(xs + (wm + i * 16 + lrow) * LDP + kbase);
#pragma unroll
        for (int j = 0; j < 4; ++j)
            b[j] = *(const half8*)(ws + (wn + j * 16 + lrow) * LDP + kbase);
#pragma unroll
        for (int i = 0; i < 4; ++i)
#pragma unroll
            for (int j = 0; j < 4; ++j)
                acc[i][j] = __builtin_amdgcn_mfma_f32_16x16x32_f16(a[i], b[j], acc[i][j], 0, 0, 0);
    }

#pragma unroll
    for (int i = 0; i < 4; ++i) {
#pragma unroll
        for (int j = 0; j < 4; ++j) {
            int col = wn + j * 16 + lrow;
            float bv_ = bias[col];
#pragma unroll
            for (int r = 0; r < 4; ++r) {
                int row = wm + i * 16 + quad * 4 + r;
                int grow = tile0 + row;
                if (grow < n) out[(size_t)grow * 128 + col] = (_Float16)(acc[i][j][r] + bv_);
            }
        }
    }
}

// ---------------- Node-centric attention: depth-2 copy-free pipeline ----------------
// p_eh = mix_eh * exp(dot/4); attn = p / sum(p). Scores bounded so no max needed.
// 8 threads/node (1 head each), 32 nodes/block, sequential node order (coalesced
// q/pi/out). 4 named K/V slots, loop body duplicated with swapped roles so the
// pipeline rotates by NAME (no v_mov register rotation, no runtime-indexed
// arrays -> no scratch). While computing edges (j,j+1): K/V+w for (j+2,j+3) in
// flight, meta (int2 edge,src) 4 ahead.

#define PREFETCH(S, idx)                                                      \
    {                                                                         \
        k##S = (half16v)(_Float16)0; v##S = (half16v)(_Float16)0;             \
        w##S##0 = 0.f; w##S##1 = 0.f; w##S##2 = 0.f;                          \
        if ((idx) < end) {                                                    \
            k##S = *(const half16v*)(kbase + (size_t)m##S.y * 128);           \
            v##S = *(const half16v*)(vbase + (size_t)m##S.y * 128);           \
            const float* vp_ = view_w + (size_t)m##S.x * 3;                   \
            w##S##0 = vp_[0]; w##S##1 = vp_[1]; w##S##2 = vp_[2];             \
        }                                                                     \
    }

#ifdef USE_FDOT2
#define DOT16(dres, kS)                                                       \
    {                                                                         \
        _Pragma("unroll")                                                     \
        for (int j_ = 0; j_ < 8; ++j_) {                                      \
            half2v a_, b_;                                                    \
            a_[0] = qv[2 * j_]; a_[1] = qv[2 * j_ + 1];                       \
            b_[0] = kS[2 * j_]; b_[1] = kS[2 * j_ + 1];                       \
            dres = __builtin_amdgcn_fdot2(a_, b_, dres, false);               \
        }                                                                     \
    }
#else
#define DOT16(dres, kS)                                                       \
    {                                                                         \
        _Pragma("unroll")                                                     \
        for (int j_ = 0; j_ < 16; ++j_)                                       \
            dres = fmaf((float)qv[j_], (float)kS[j_], dres);                  \
    }
#endif

#define COMPUTE(S, eidx, valid)                                               \
    {                                                                         \
        float mix_ = fmaf(p0, w##S##0, fmaf(p1, w##S##1, p2 * w##S##2));      \
        float d_ = 0.f;                                                       \
        DOT16(d_, k##S);                                                      \
        float p_ = (mix_ > 0.f) ? mix_ * __expf(d_ * 0.25f) : 0.f;            \
        if (valid) pbuf[(size_t)(eidx)*8 + h] = (_Float16)p_;                 \
        l += p_;                                                              \
        _Pragma("unroll")                                                     \
        for (int j_ = 0; j_ < 16; ++j_)                                       \
            acc[j_] = fmaf(p_, (float)v##S[j_], acc[j_]);                     \
    }

// computes edges (jj, jj+1) from slots S0,S1; prefetches (jj+2, jj+3) into
// S2,S3; loads meta (jj+4, jj+5) into the S0,S1 meta slots for the next body.
#define BODY(S0, S1, S2, S3, jj)                                              \
    {                                                                         \
        PREFETCH(S2, (jj) + 2);                                               \
        PREFETCH(S3, (jj) + 3);                                               \
        int eA_ = m##S0.x, eB_ = m##S1.x;                                     \
        m##S0 = make_int2(0, 0); m##S1 = make_int2(0, 0);                     \
        if ((jj) + 4 < end) m##S0 = csr2[(jj) + 4];                           \
        if ((jj) + 5 < end) m##S1 = csr2[(jj) + 5];                           \
        COMPUTE(S0, eA_, true);                                               \
        COMPUTE(S1, eB_, (jj) + 1 < end);                                     \
    }

__global__ __launch_bounds__(256) void edge_attn(
    const _Float16* __restrict__ qh, const _Float16* __restrict__ kh,
    const _Float16* __restrict__ vh, const float* __restrict__ pi,
    const float* __restrict__ view_w,
    const int* __restrict__ row_ptr, const int2* __restrict__ csr2,
    float* __restrict__ node_out, float* __restrict__ invb,
    _Float16* __restrict__ pbuf, int n) {
    int t = threadIdx.x;
    int node = blockIdx.x * 32 + (t >> 3);
    if (node >= n) return;
    int h = t & 7;

    const half16v qv = *(const half16v*)(qh + (size_t)node * 128 + h * 16);
    const _Float16* kbase = kh + h * 16;
    const _Float16* vbase = vh + h * 16;

    float p0 = pi[node * 24 + h * 3 + 0];
    float p1 = pi[node * 24 + h * 3 + 1];
    float p2 = pi[node * 24 + h * 3 + 2];
    int beg = row_ptr[node], end = row_ptr[node + 1];

    float l = 0.f;
    float acc[16];
#pragma unroll
    for (int j = 0; j < 16; ++j) acc[j] = 0.f;

    int2 mA = make_int2(0, 0), mB = make_int2(0, 0);
    int2 mC = make_int2(0, 0), mD = make_int2(0, 0);
    float wA0 = 0.f, wA1 = 0.f, wA2 = 0.f, wB0 = 0.f, wB1 = 0.f, wB2 = 0.f;
    float wC0 = 0.f, wC1 = 0.f, wC2 = 0.f, wD0 = 0.f, wD1 = 0.f, wD2 = 0.f;
    half16v kA = (half16v)(_Float16)0, vA = kA, kB = kA, vB = kA;
    half16v kC = kA, vC = kA, kD = kA, vD = kA;

    if (beg < end)     mA = csr2[beg];
    if (beg + 1 < end) mB = csr2[beg + 1];
    if (beg + 2 < end) mC = csr2[beg + 2];
    if (beg + 3 < end) mD = csr2[beg + 3];
    PREFETCH(A, beg);
    PREFETCH(B, beg + 1);

    for (int j = beg; j < end;) {
        BODY(A, B, C, D, j);
        j += 2;
        if (j >= end) break;
        BODY(C, D, A, B, j);
        j += 2;
    }

    float inv = 1.f / fmaxf(l, 1e-8f);
    invb[(size_t)node * 8 + h] = inv;

    float4* op = (float4*)(node_out + (size_t)node * 128 + h * 16);
#pragma unroll
    for (int j = 0; j < 4; ++j)
        op[j] = make_float4(acc[4 * j] * inv, acc[4 * j + 1] * inv,
                            acc[4 * j + 2] * inv, acc[4 * j + 3] * inv);
}

// ---------------- edge-parallel attention normalize (coalesced) ----------------

__global__ __launch_bounds__(256) void attn_norm(
    const _Float16* __restrict__ pbuf, const int* __restrict__ dst,
    const float* __restrict__ invb, float* __restrict__ attn_out, int e) {
    int i = blockIdx.x * blockDim.x + threadIdx.x;
    if (i < e) {
        int d = dst[i];
        half8 p = *((const half8*)pbuf + i);
        const float4* iv = (const float4*)(invb + (size_t)d * 8);
        float4 i0 = iv[0], i1 = iv[1];
        float4* op = (float4*)(attn_out + (size_t)i * 8);
        op[0] = make_float4((float)p[0] * i0.x, (float)p[1] * i0.y,
                            (float)p[2] * i0.z, (float)p[3] * i0.w);
        op[1] = make_float4((float)p[4] * i1.x, (float)p[5] * i1.y,
                            (float)p[6] * i1.z, (float)p[7] * i1.w);
    }
}

// ---------------- launch ----------------

extern "C" void kernel_launch(void* const* d_in, const int* in_sizes, int n_in,
                              void* d_out, int out_size, void* d_ws, size_t ws_size,
                              hipStream_t stream) {
    const float* x  = (const float*)d_in[0];
    const float* pi = (const float*)d_in[1];
    const float* vw = (const float*)d_in[2];
    const float* Wq = (const float*)d_in[3];
    const float* bq = (const float*)d_in[4];
    const float* Wk = (const float*)d_in[5];
    const float* bk = (const float*)d_in[6];
    const float* Wv = (const float*)d_in[7];
    const float* bv = (const float*)d_in[8];
    const int* src  = (const int*)d_in[9];
    const int* dst  = (const int*)d_in[10];

    int n = in_sizes[0] / 128;  // 100000
    int e = in_sizes[9];        // 1600000

    _Float16* xh = (_Float16*)d_ws;
    _Float16* qh = xh + (size_t)n * 128;
    _Float16* kh = qh + (size_t)n * 128;
    _Float16* vh = kh + (size_t)n * 128;
    _Float16* wt = vh + (size_t)n * 128;
    _Float16* pbuf = wt + 3 * 16384;
    float* invb  = (float*)(pbuf + (size_t)e * 8);
    int* counts  = (int*)(invb + (size_t)n * 8);
    int* cursor  = counts + n;
    int* row_ptr = cursor + n;
    int* bsum    = row_ptr + n + 1;

    float* node_out = (float*)d_out;
    float* attn_out = node_out + (size_t)n * 128;
    // csr2 scratch lives in the attn output region: written by fill_csr,
    // consumed by edge_attn, fully overwritten by attn_norm afterwards.
    int2* csr2 = (int2*)attn_out;

    hipMemsetAsync(counts, 0, (size_t)n * sizeof(int), stream);

    int eb = (e + 255) / 256;
    hist_kernel<<<eb, 256, 0, stream>>>(dst, counts, e);

    int nb = (n + SCAN_CHUNK - 1) / SCAN_CHUNK;  // 49
    scan_block_sums<<<nb, 256, 0, stream>>>(counts, bsum, n);
    scan_wave<<<1, 64, 0, stream>>>(bsum, nb);
    scan_write<<<nb, 256, 0, stream>>>(counts, bsum, row_ptr, cursor, n, e);
    fill_csr<<<eb, 256, 0, stream>>>(dst, src, cursor, csr2, e);

    int tot8 = (n * 128) / 8;
    convert_x<<<(tot8 + 255) / 256, 256, 0, stream>>>(x, xh, tot8);
    prep_w<<<3, 256, 0, stream>>>(Wq, Wk, Wv, wt);

    int gtiles = (n + 127) / 128;
    qkv_mfma<<<dim3(gtiles, 3), 256, 0, stream>>>(xh, wt, bq, bk, bv, qh, kh, vh, n);

    int gb = (n + 31) / 32;
    edge_attn<<<gb, 256, 0, stream>>>(qh, kh, vh, pi, vw, row_ptr, csr2,
                                      node_out, invb, pbuf, n);
    attn_norm<<<eb, 256, 0, stream>>>(pbuf, dst, invb, attn_out, e);
}